// Round 3
// baseline (575.139 us; speedup 1.0000x reference)
//
#include <hip/hip_runtime.h>
#include <stdint.h>

#define BATCH 32768
#define NN    2500
#define NPAD  2560
#define DIM   256

#define BM 128
#define BN 128

typedef __attribute__((ext_vector_type(8))) short short8;
typedef __attribute__((ext_vector_type(4))) float float4_;

__device__ __forceinline__ unsigned short f2bf(float f) {
  union { float f; uint32_t u; } v; v.f = f;
  uint32_t u = v.u;
  return (unsigned short)((u + 0x7FFFu + ((u >> 16) & 1u)) >> 16);
}

// ---------------- prep: fp32 -> bf16 copy + exact fp32 row norm ----------------
__global__ void prep_rows2(const float* __restrict__ xin, const float* __restrict__ win_,
                           unsigned short* __restrict__ outb, float* __restrict__ sq) {
  int row  = blockIdx.x * 4 + (threadIdx.x >> 6);
  int lane = threadIdx.x & 63;
  float4 v = make_float4(0.f, 0.f, 0.f, 0.f);
  if (row < BATCH) {
    v = ((const float4*)(xin + (size_t)row * DIM))[lane];
  } else if (row - BATCH < NN) {
    v = ((const float4*)(win_ + (size_t)(row - BATCH) * DIM))[lane];
  }
  float s = v.x * v.x + v.y * v.y + v.z * v.z + v.w * v.w;
  *(ushort4*)(outb + (size_t)row * DIM + lane * 4) =
      make_ushort4(f2bf(v.x), f2bf(v.y), f2bf(v.z), f2bf(v.w));
  for (int off = 32; off > 0; off >>= 1) s += __shfl_down(s, off, 64);
  if (lane == 0) sq[row] = s;
}

// ---------------- main GEMM: NO LDS, NO barriers — direct-from-L2 fragments ----------------
// W (1.31 MB bf16) is L2-resident per XCD (XCD-chunked grid, N-inner), and the
// per-XCD X slice (2 MB) likewise. So B/A fragments are loaded straight from
// global (L2-hit) each K-step: zero __syncthreads, zero vmcnt(0) drains in the
// body, zero LDS -> occupancy is VGPR-limited only (cap 85 -> 24 waves/CU,
// 1.5x the LDS version). Fully-unrolled K-loop: with no barriers the compiler
// hoists loads as deep as registers allow (counted vmcnt, never drained).
// 8 waves (4x2): wave = 32 rows x 64 cols, acc[2][4].
__global__ __launch_bounds__(512, 6)
void cdist_gemm_bf16(const unsigned short* __restrict__ Xb,
                     const unsigned short* __restrict__ Wb,
                     const float* __restrict__ xsq, const float* __restrict__ wsq,
                     float* __restrict__ out) {
  const int tid  = threadIdx.x;
  const int lane = tid & 63;
  const int wave = tid >> 6;                 // 0..7

  // XCD-chunked mapping: 5120 blocks = 8 XCDs x 640; per XCD 32 M-tiles x 20
  // N-tiles, N inner.
  const int bid = blockIdx.x;
  const int loc = bid >> 3;                  // 0..639
  const int mt  = (bid & 7) * 32 + loc / 20; // 0..255
  const int nt  = loc % 20;                  // 0..19
  const int m0  = mt * BM;
  const int n0  = nt * BN;

  const int wr = wave >> 1;                  // 0..3  (32-row slice)
  const int wc = wave & 1;                   // 0..1  (64-col slice)
  const int q  = lane >> 4;                  // k-chunk 0..3
  const int i  = lane & 15;

  // per-lane fragment bases: MFMA A/B layout = lane(q,i) holds 8 bf16 of
  // row/col i at k = ks*32 + q*8 (16-B aligned; rows are 512 B).
  const unsigned short* gA = Xb + (size_t)(m0 + wr * 32 + i) * DIM + q * 8;
  const unsigned short* gB = Wb + (size_t)(n0 + wc * 64 + i) * DIM + q * 8;

  float4_ acc[2][4] = {};

#pragma unroll
  for (int ks = 0; ks < 8; ++ks) {
    const int o = ks * 32;
    short8 a0 = *(const short8*)(gA + o);
    short8 a1 = *(const short8*)(gA + 16 * DIM + o);
    short8 b0 = *(const short8*)(gB + o);
    short8 b1 = *(const short8*)(gB + 16 * DIM + o);
    short8 b2 = *(const short8*)(gB + 32 * DIM + o);
    short8 b3 = *(const short8*)(gB + 48 * DIM + o);

    acc[0][0] = __builtin_amdgcn_mfma_f32_16x16x32_bf16(a0, b0, acc[0][0], 0, 0, 0);
    acc[1][0] = __builtin_amdgcn_mfma_f32_16x16x32_bf16(a1, b0, acc[1][0], 0, 0, 0);
    acc[0][1] = __builtin_amdgcn_mfma_f32_16x16x32_bf16(a0, b1, acc[0][1], 0, 0, 0);
    acc[1][1] = __builtin_amdgcn_mfma_f32_16x16x32_bf16(a1, b1, acc[1][1], 0, 0, 0);
    acc[0][2] = __builtin_amdgcn_mfma_f32_16x16x32_bf16(a0, b2, acc[0][2], 0, 0, 0);
    acc[1][2] = __builtin_amdgcn_mfma_f32_16x16x32_bf16(a1, b2, acc[1][2], 0, 0, 0);
    acc[0][3] = __builtin_amdgcn_mfma_f32_16x16x32_bf16(a0, b3, acc[0][3], 0, 0, 0);
    acc[1][3] = __builtin_amdgcn_mfma_f32_16x16x32_bf16(a1, b3, acc[1][3], 0, 0, 0);
  }

  // epilogue: d = sqrt(max(xsq + wsq - 2*cross, 0))
  // C/D layout: col = lane&15, row = (lane>>4)*4 + reg  [m89/m91]
  // plain stores (NT stores cost +49% WRITE_SIZE in round 1).
#pragma unroll
  for (int ti = 0; ti < 2; ++ti) {
    int grow_base = m0 + wr * 32 + ti * 16 + q * 4;
#pragma unroll
    for (int tj = 0; tj < 4; ++tj) {
      int gcol = n0 + wc * 64 + tj * 16 + i;
      if (gcol < NN) {
        float wn = wsq[gcol];
#pragma unroll
        for (int r = 0; r < 4; ++r) {
          int grow = grow_base + r;
          float d2 = xsq[grow] + wn - 2.0f * acc[ti][tj][r];
          out[(size_t)grow * NN + gcol] = sqrtf(fmaxf(d2, 0.f));
        }
      }
    }
  }
}

// ---------------- fallback path (ws too small): round-1 kernels ----------------
#define LDA 72
#define BKF 64
__global__ void row_sq_norm(const float* __restrict__ in, float* __restrict__ out,
                            int nrows, int nvalid) {
  int row  = blockIdx.x * 4 + (threadIdx.x >> 6);
  int lane = threadIdx.x & 63;
  if (row >= nrows) return;
  float s = 0.f;
  if (row < nvalid) {
    float4 v = ((const float4*)(in + (size_t)row * DIM))[lane];
    s = v.x * v.x + v.y * v.y + v.z * v.z + v.w * v.w;
  }
  for (int off = 32; off > 0; off >>= 1) s += __shfl_down(s, off, 64);
  if (lane == 0) out[row] = s;
}

__global__ __launch_bounds__(256, 2)
void cdist_gemm_f32(const float* __restrict__ X, const float* __restrict__ W,
                    const float* __restrict__ xsq, const float* __restrict__ wsq,
                    float* __restrict__ out) {
  __shared__ __align__(16) unsigned short As[BM * LDA];
  __shared__ __align__(16) unsigned short Bs2[BN * LDA];
  const int tid = threadIdx.x, lane = tid & 63, wave = tid >> 6;
  const int m0 = blockIdx.x * BM, n0 = blockIdx.y * BN;
  const int wr = wave >> 1, wc = wave & 1;
  float4_ acc[4][4] = {};
  const int s_col4 = tid & 15, s_row0 = tid >> 4;
  for (int kc = 0; kc < DIM; kc += BKF) {
#pragma unroll
    for (int j = 0; j < 8; ++j) {
      int r = s_row0 + 16 * j;
      float4 v = *(const float4*)(X + (size_t)(m0 + r) * DIM + kc + s_col4 * 4);
      *(ushort4*)&As[r * LDA + s_col4 * 4] =
          make_ushort4(f2bf(v.x), f2bf(v.y), f2bf(v.z), f2bf(v.w));
    }
#pragma unroll
    for (int j = 0; j < 8; ++j) {
      int r = s_row0 + 16 * j, n = n0 + r;
      float4 v = make_float4(0.f, 0.f, 0.f, 0.f);
      if (n < NN) v = *(const float4*)(W + (size_t)n * DIM + kc + s_col4 * 4);
      *(ushort4*)&Bs2[r * LDA + s_col4 * 4] =
          make_ushort4(f2bf(v.x), f2bf(v.y), f2bf(v.z), f2bf(v.w));
    }
    __syncthreads();
    const int q = lane >> 4, i = lane & 15;
#pragma unroll
    for (int ks = 0; ks < BKF; ks += 32) {
      short8 a[4], b[4];
#pragma unroll
      for (int t = 0; t < 4; ++t) {
        a[t] = *(const short8*)&As[(wr * 64 + t * 16 + i) * LDA + ks + q * 8];
        b[t] = *(const short8*)&Bs2[(wc * 64 + t * 16 + i) * LDA + ks + q * 8];
      }
#pragma unroll
      for (int ti = 0; ti < 4; ++ti)
#pragma unroll
        for (int tj = 0; tj < 4; ++tj)
          acc[ti][tj] = __builtin_amdgcn_mfma_f32_16x16x32_bf16(
              a[ti], b[tj], acc[ti][tj], 0, 0, 0);
    }
    __syncthreads();
  }
  const int q = lane >> 4, i = lane & 15;
#pragma unroll
  for (int ti = 0; ti < 4; ++ti) {
    int grow_base = m0 + wr * 64 + ti * 16 + q * 4;
#pragma unroll
    for (int tj = 0; tj < 4; ++tj) {
      int gcol = n0 + wc * 64 + tj * 16 + i;
      if (gcol < NN) {
        float wn = wsq[gcol];
#pragma unroll
        for (int r = 0; r < 4; ++r) {
          int grow = grow_base + r;
          float d2 = xsq[grow] + wn - 2.0f * acc[ti][tj][r];
          out[(size_t)grow * NN + gcol] = sqrtf(fmaxf(d2, 0.f));
        }
      }
    }
  }
}

extern "C" void kernel_launch(void* const* d_in, const int* in_sizes, int n_in,
                              void* d_out, int out_size, void* d_ws, size_t ws_size,
                              hipStream_t stream) {
  const float* x = (const float*)d_in[0];
  const float* w = (const float*)d_in[1];

  const size_t xb_elems = (size_t)BATCH * DIM;          // bf16
  const size_t wb_elems = (size_t)NPAD * DIM;           // bf16
  const size_t need = xb_elems * 2 + wb_elems * 2 + (size_t)BATCH * 4 + (size_t)NPAD * 4;

  if (ws_size >= need) {
    unsigned short* Xb = (unsigned short*)d_ws;
    unsigned short* Wb = Xb + xb_elems;
    float* xsq = (float*)(Wb + wb_elems);
    float* wsq = xsq + BATCH;

    prep_rows2<<<(BATCH + NPAD) / 4, 256, 0, stream>>>(x, w, Xb, xsq);

    cdist_gemm_bf16<<<dim3((BATCH / BM) * (NPAD / BN)), 512, 0, stream>>>(
        Xb, Wb, xsq, wsq, (float*)d_out);
  } else {
    float* xsq = (float*)d_ws;
    float* wsq = xsq + BATCH;
    row_sq_norm<<<BATCH / 4, 256, 0, stream>>>(x, xsq, BATCH, BATCH);
    row_sq_norm<<<NPAD / 4, 256, 0, stream>>>(w, wsq, NPAD, NN);
    dim3 grid(BATCH / BM, NPAD / BN);
    cdist_gemm_f32<<<grid, 256, 0, stream>>>(x, w, xsq, wsq, (float*)d_out);
  }
}

// Round 4
// 436.876 us; speedup vs baseline: 1.3165x; 1.3165x over previous
//
#include <hip/hip_runtime.h>
#include <stdint.h>

#define BATCH 32768
#define NN    2500
#define NPAD  2560
#define DIM   256

#define BM 256
#define BN 256

typedef __attribute__((ext_vector_type(8))) short short8;
typedef __attribute__((ext_vector_type(4))) float float4_;

__device__ __forceinline__ unsigned short f2bf(float f) {
  union { float f; uint32_t u; } v; v.f = f;
  uint32_t u = v.u;
  return (unsigned short)((u + 0x7FFFu + ((u >> 16) & 1u)) >> 16);
}

__device__ __forceinline__ void gload_lds16(const void* g, void* lds) {
  __builtin_amdgcn_global_load_lds(
      (const __attribute__((address_space(1))) unsigned int*)g,
      (__attribute__((address_space(3))) unsigned int*)lds, 16, 0, 0);
}

// ---------------- prep: fp32 -> bf16 copy + exact fp32 row norm ----------------
__global__ void prep_rows2(const float* __restrict__ xin, const float* __restrict__ win_,
                           unsigned short* __restrict__ outb, float* __restrict__ sq) {
  int row  = blockIdx.x * 4 + (threadIdx.x >> 6);
  int lane = threadIdx.x & 63;
  float4 v = make_float4(0.f, 0.f, 0.f, 0.f);
  if (row < BATCH) {
    v = ((const float4*)(xin + (size_t)row * DIM))[lane];
  } else if (row - BATCH < NN) {
    v = ((const float4*)(win_ + (size_t)(row - BATCH) * DIM))[lane];
  }
  float s = v.x * v.x + v.y * v.y + v.z * v.z + v.w * v.w;
  *(ushort4*)(outb + (size_t)row * DIM + lane * 4) =
      make_ushort4(f2bf(v.x), f2bf(v.y), f2bf(v.z), f2bf(v.w));
  for (int off = 32; off > 0; off >>= 1) s += __shfl_down(s, off, 64);
  if (lane == 0) sq[row] = s;
}

// ---------------- main GEMM: 256x256 tiles, B-panel resident in LDS ----------------
// Tile-size is the lever: staged-read traffic = #blocks*(A+B panel).
// 128x128 tiles: 5120 blocks x ~192KB ~= 1 GB through L2/L3. 256x256 tiles:
// 1280 blocks x 256KB = 328 MB (3x less), 5 block-rounds/CU instead of 20.
// Schedule = round-2's proven shape: whole B panel (256x256 bf16 = 128 KB,
// fits 160 KB/CU) staged to LDS ONCE with pre-swizzled source, single
// __syncthreads, then barrier-free K-loop with A streamed global->reg
// (L1-resident: per-K-step A slice is 8 KB, read by 2 waves).
// launch_bounds(512,2): VGPR cap 256 so the allocator keeps acc[4][8] (128)
// + a[4]+b[8] (48) live — round 3's 36-VGPR starvation came from (512,6).
// Swizzle: physical 16B-chunk pc of LDS row r holds logical chunk pc^(r&7);
// read slot = (ks*4+q)^(i&7) -> 8 slot-groups x 4 banks, 8 lanes each ->
// conflict-free ds_read_b128 (verified shape in r2: SQ_LDS_BANK_CONFLICT=0).
__global__ __launch_bounds__(512, 2)
void cdist_gemm_bf16(const unsigned short* __restrict__ Xb,
                     const unsigned short* __restrict__ Wb,
                     const float* __restrict__ xsq, const float* __restrict__ wsq,
                     float* __restrict__ out) {
  __shared__ __align__(16) unsigned short Bs[BN * DIM];   // 128 KB

  const int tid  = threadIdx.x;
  const int lane = tid & 63;
  const int wave = tid >> 6;                 // 0..7

  // XCD-chunked mapping: 1280 blocks = 8 XCDs x 160; per XCD 16 M-tiles x 10
  // N-tiles, N inner -> per-XCD set = X slice (2 MB) + W (1.31 MB) < 4 MB L2.
  const int bid = blockIdx.x;
  const int loc = bid >> 3;                  // 0..159
  const int mt  = (bid & 7) * 16 + loc / 10; // 0..127
  const int nt  = loc % 10;                  // 0..9
  const int m0  = mt * BM;
  const int n0  = nt * BN;

  const int wr = wave >> 1;                  // 0..3  (64-row slice)
  const int wc = wave & 1;                   // 0..1  (128-col slice)
  const int q  = lane >> 4;                  // k-chunk 0..3
  const int i  = lane & 15;

  // ---- stage whole B panel once: 8192 16B chunks, linear LDS dest,
  //      pre-swizzled global source (chunk lc = pc ^ (row&7)) ----
#pragma unroll
  for (int j = 0; j < 16; ++j) {
    int c   = j * 512 + tid;                 // chunk id 0..8191
    int row = c >> 5;                        // 32 chunks per 512B row
    int pc  = c & 31;
    int lc  = pc ^ (row & 7);
    gload_lds16(Wb + (size_t)(n0 + row) * DIM + lc * 8, &Bs[c * 8]);
  }

  // per-lane A base: rows (m0 + wr*64 + i + {0,16,32,48}), k-chunk q
  const unsigned short* gA = Xb + (size_t)(m0 + wr * 64 + i) * DIM + q * 8;

  float4_ acc[4][8] = {};

  __syncthreads();   // the ONLY barrier: B panel resident from here on

#pragma unroll
  for (int ks = 0; ks < 8; ++ks) {
    short8 a[4], b[8];
#pragma unroll
    for (int t = 0; t < 4; ++t)
      a[t] = *(const short8*)(gA + (size_t)(t * 16) * DIM + ks * 32);
#pragma unroll
    for (int tj = 0; tj < 8; ++tj) {
      int row = wc * 128 + tj * 16 + i;
      int pc  = (ks * 4 + q) ^ (i & 7);
      b[tj] = *(const short8*)&Bs[(row << 8) + (pc << 3)];
    }
#pragma unroll
    for (int ti = 0; ti < 4; ++ti)
#pragma unroll
      for (int tj = 0; tj < 8; ++tj)
        acc[ti][tj] = __builtin_amdgcn_mfma_f32_16x16x32_bf16(
            a[ti], b[tj], acc[ti][tj], 0, 0, 0);
  }

  // epilogue: d = sqrt(max(xsq + wsq - 2*cross, 0))
  // C/D layout: col = lane&15, row = (lane>>4)*4 + reg  [m89/m91]
  // plain stores (NT partial-line stores cost +49% WRITE_SIZE in round 1).
#pragma unroll
  for (int ti = 0; ti < 4; ++ti) {
    int grow_base = m0 + wr * 64 + ti * 16 + q * 4;
    float xr[4];
#pragma unroll
    for (int r = 0; r < 4; ++r) xr[r] = xsq[grow_base + r];
#pragma unroll
    for (int tj = 0; tj < 8; ++tj) {
      int gcol = n0 + wc * 128 + tj * 16 + i;
      if (gcol < NN) {
        float wn = wsq[gcol];
#pragma unroll
        for (int r = 0; r < 4; ++r) {
          int grow = grow_base + r;
          float d2 = xr[r] + wn - 2.0f * acc[ti][tj][r];
          out[(size_t)grow * NN + gcol] = sqrtf(fmaxf(d2, 0.f));
        }
      }
    }
  }
}

// ---------------- fallback path (ws too small): round-1 kernels ----------------
#define LDA 72
#define BKF 64
#define BMF 128
#define BNF 128
__global__ void row_sq_norm(const float* __restrict__ in, float* __restrict__ out,
                            int nrows, int nvalid) {
  int row  = blockIdx.x * 4 + (threadIdx.x >> 6);
  int lane = threadIdx.x & 63;
  if (row >= nrows) return;
  float s = 0.f;
  if (row < nvalid) {
    float4 v = ((const float4*)(in + (size_t)row * DIM))[lane];
    s = v.x * v.x + v.y * v.y + v.z * v.z + v.w * v.w;
  }
  for (int off = 32; off > 0; off >>= 1) s += __shfl_down(s, off, 64);
  if (lane == 0) out[row] = s;
}

__global__ __launch_bounds__(256, 2)
void cdist_gemm_f32(const float* __restrict__ X, const float* __restrict__ W,
                    const float* __restrict__ xsq, const float* __restrict__ wsq,
                    float* __restrict__ out) {
  __shared__ __align__(16) unsigned short As[BMF * LDA];
  __shared__ __align__(16) unsigned short Bs2[BNF * LDA];
  const int tid = threadIdx.x, lane = tid & 63, wave = tid >> 6;
  const int m0 = blockIdx.x * BMF, n0 = blockIdx.y * BNF;
  const int wr = wave >> 1, wc = wave & 1;
  float4_ acc[4][4] = {};
  const int s_col4 = tid & 15, s_row0 = tid >> 4;
  for (int kc = 0; kc < DIM; kc += BKF) {
#pragma unroll
    for (int j = 0; j < 8; ++j) {
      int r = s_row0 + 16 * j;
      float4 v = *(const float4*)(X + (size_t)(m0 + r) * DIM + kc + s_col4 * 4);
      *(ushort4*)&As[r * LDA + s_col4 * 4] =
          make_ushort4(f2bf(v.x), f2bf(v.y), f2bf(v.z), f2bf(v.w));
    }
#pragma unroll
    for (int j = 0; j < 8; ++j) {
      int r = s_row0 + 16 * j, n = n0 + r;
      float4 v = make_float4(0.f, 0.f, 0.f, 0.f);
      if (n < NN) v = *(const float4*)(W + (size_t)n * DIM + kc + s_col4 * 4);
      *(ushort4*)&Bs2[r * LDA + s_col4 * 4] =
          make_ushort4(f2bf(v.x), f2bf(v.y), f2bf(v.z), f2bf(v.w));
    }
    __syncthreads();
    const int q = lane >> 4, i = lane & 15;
#pragma unroll
    for (int ks = 0; ks < BKF; ks += 32) {
      short8 a[4], b[4];
#pragma unroll
      for (int t = 0; t < 4; ++t) {
        a[t] = *(const short8*)&As[(wr * 64 + t * 16 + i) * LDA + ks + q * 8];
        b[t] = *(const short8*)&Bs2[(wc * 64 + t * 16 + i) * LDA + ks + q * 8];
      }
#pragma unroll
      for (int ti = 0; ti < 4; ++ti)
#pragma unroll
        for (int tj = 0; tj < 4; ++tj)
          acc[ti][tj] = __builtin_amdgcn_mfma_f32_16x16x32_bf16(
              a[ti], b[tj], acc[ti][tj], 0, 0, 0);
    }
    __syncthreads();
  }
  const int q = lane >> 4, i = lane & 15;
#pragma unroll
  for (int ti = 0; ti < 4; ++ti) {
    int grow_base = m0 + wr * 64 + ti * 16 + q * 4;
#pragma unroll
    for (int tj = 0; tj < 4; ++tj) {
      int gcol = n0 + wc * 64 + tj * 16 + i;
      if (gcol < NN) {
        float wn = wsq[gcol];
#pragma unroll
        for (int r = 0; r < 4; ++r) {
          int grow = grow_base + r;
          float d2 = xsq[grow] + wn - 2.0f * acc[ti][tj][r];
          out[(size_t)grow * NN + gcol] = sqrtf(fmaxf(d2, 0.f));
        }
      }
    }
  }
}

extern "C" void kernel_launch(void* const* d_in, const int* in_sizes, int n_in,
                              void* d_out, int out_size, void* d_ws, size_t ws_size,
                              hipStream_t stream) {
  const float* x = (const float*)d_in[0];
  const float* w = (const float*)d_in[1];

  const size_t xb_elems = (size_t)BATCH * DIM;          // bf16
  const size_t wb_elems = (size_t)NPAD * DIM;           // bf16
  const size_t need = xb_elems * 2 + wb_elems * 2 + (size_t)BATCH * 4 + (size_t)NPAD * 4;

  if (ws_size >= need) {
    unsigned short* Xb = (unsigned short*)d_ws;
    unsigned short* Wb = Xb + xb_elems;
    float* xsq = (float*)(Wb + wb_elems);
    float* wsq = xsq + BATCH;

    prep_rows2<<<(BATCH + NPAD) / 4, 256, 0, stream>>>(x, w, Xb, xsq);

    cdist_gemm_bf16<<<dim3((BATCH / BM) * (NPAD / BN)), 512, 0, stream>>>(
        Xb, Wb, xsq, wsq, (float*)d_out);
  } else {
    float* xsq = (float*)d_ws;
    float* wsq = xsq + BATCH;
    row_sq_norm<<<BATCH / 4, 256, 0, stream>>>(x, xsq, BATCH, BATCH);
    row_sq_norm<<<NPAD / 4, 256, 0, stream>>>(w, wsq, NPAD, NN);
    dim3 grid(BATCH / BMF, NPAD / BNF);
    cdist_gemm_f32<<<grid, 256, 0, stream>>>(x, w, xsq, wsq, (float*)d_out);
  }
}